// Round 9
// baseline (345.430 us; speedup 1.0000x reference)
//
#include <hip/hip_runtime.h>
#include <hip/hip_bf16.h>

#define TT 4096
#define DD 1024
#define TBB 1024
#define WBB 256

typedef __attribute__((ext_vector_type(8))) _Float16 half8;
typedef __attribute__((ext_vector_type(4))) _Float16 half4;
typedef __attribute__((ext_vector_type(16))) float f32x16;

__device__ __forceinline__ unsigned short f2h(float v) {
  _Float16 h = (_Float16)v;
  return *reinterpret_cast<unsigned short*>(&h);
}
__device__ __forceinline__ float h2f(unsigned short u) {
  _Float16 h = *reinterpret_cast<_Float16*>(&u);
  return (float)h;
}

__device__ __forceinline__ void gl_lds16(const unsigned short* g, unsigned short* l) {
  __builtin_amdgcn_global_load_lds(
      (const __attribute__((address_space(1))) void*)(unsigned long long)(g),
      (__attribute__((address_space(3))) void*)(unsigned long long)(l),
      16, 0, 0);
}

__device__ __forceinline__ float waveSum(float v) {
#pragma unroll
  for (int o = 32; o > 0; o >>= 1) v += __shfl_down(v, o, 64);
  return v;
}
__device__ __forceinline__ float waveMax(float v) {
#pragma unroll
  for (int o = 32; o > 0; o >>= 1) v = fmaxf(v, __shfl_down(v, o, 64));
  return v;
}

// Fully-direct, BARRIER-FREE GEMM: C = A (MxK row-major) * Bf^T.
// A fragments loaded straight global->VGPR (lane l31 = row, khi*8 = k-sub);
// Bf in MFMA-fragment order: half8 index ((q*Gtot+g)*64 + lane) holds
// B[n=g*32+l31][k=q*16+khi*8+j]. No LDS, no __syncthreads in the K-loop:
// compiler emits fine-grained vmcnt, waves run fully decoupled.
// 128x128 tile, 4 waves in 64x64 quadrants, mfma 32x32x16 f16.
// EPI: 0 plain, 1 -> 1-acc, 2 -> +aph (fp16 abs-pos), 3 -> +ent/dep cols
template <int EPI, typename OutT>
__global__ __launch_bounds__(256, 3) void gemm_dd(
    const unsigned short* __restrict__ A, const unsigned short* __restrict__ Bf,
    OutT* __restrict__ C,
    int K, int lda, int ldc, int Gtot, int zdiv,
    long sAi, long sAj, long sBz, long sCi, long sCj,
    const float* __restrict__ e0, const float* __restrict__ e1,
    const float* __restrict__ e2, const float* __restrict__ e3,
    const unsigned short* __restrict__ aph)
{
  const int z = blockIdx.z;
  const int zi = z / zdiv, zj = z - zi * zdiv;
  const unsigned short* Ab = A + (long)zi * sAi + (long)zj * sAj;
  const half8* Bp = (const half8*)Bf + (long)z * sBz;  // sBz in half8 units
  const long offC = (long)zi * sCi + (long)zj * sCj;

  const int m0 = blockIdx.y * 128, n0 = blockIdx.x * 128;
  const int tid = threadIdx.x, wave = tid >> 6, lane = tid & 63;
  const int wm = (wave >> 1) * 64, wn = (wave & 1) * 64;
  const int l31 = lane & 31, khi = lane >> 5;
  const int gbase = (n0 + wn) >> 5;

  const unsigned short* arow0 = Ab + (long)(m0 + wm + l31) * lda + khi * 8;
  const unsigned short* arow1 = arow0 + (long)32 * lda;

  f32x16 acc[2][2] = {};

  for (int k0 = 0; k0 < K; k0 += 64) {
    half8 af[2][4], bf[2][4];
    const int q0 = k0 >> 4;
#pragma unroll
    for (int ks = 0; ks < 4; ++ks) {
      af[0][ks] = *(const half8*)(arow0 + k0 + ks * 16);
      af[1][ks] = *(const half8*)(arow1 + k0 + ks * 16);
      bf[0][ks] = Bp[((long)(q0 + ks) * Gtot + gbase) * 64 + lane];
      bf[1][ks] = Bp[((long)(q0 + ks) * Gtot + gbase + 1) * 64 + lane];
    }
#pragma unroll
    for (int ks = 0; ks < 4; ++ks)
#pragma unroll
      for (int mi = 0; mi < 2; ++mi)
#pragma unroll
        for (int ni = 0; ni < 2; ++ni)
          acc[mi][ni] = __builtin_amdgcn_mfma_f32_32x32x16_f16(af[mi][ks], bf[ni][ks], acc[mi][ni], 0, 0, 0);
  }

  OutT* Cb = C + offC;
#pragma unroll
  for (int mi = 0; mi < 2; ++mi)
#pragma unroll
    for (int ni = 0; ni < 2; ++ni)
#pragma unroll
      for (int r = 0; r < 16; ++r) {
        const int row = m0 + wm + mi * 32 + khi * 4 + (r & 3) + 8 * (r >> 2);
        const int col = n0 + wn + ni * 32 + l31;
        float v = acc[mi][ni][r];
        if constexpr (EPI == 1) v = 1.0f - v;
        if constexpr (EPI == 2) v += h2f(aph[(long)row * 1024 + col]);
        if constexpr (EPI == 3)
          v += e0[(long)z * 1024 + row] * e2[col] + e1[(long)z * 1024 + row] * e3[col];
        const long ci = (long)row * ldc + col;
        if constexpr (sizeof(OutT) == 2) {
          Cb[ci] = (OutT)f2h(v);
        } else {
          Cb[ci] = v;
        }
      }
}

// K (row-major [4096,1024]) -> Kf fragment order per gz block:
// gz=(zi,zj): B[n=key row local][k=feature local 0..256).
__global__ __launch_bounds__(256) void kf_reshape(const unsigned short* __restrict__ K,
                                                 unsigned short* __restrict__ Kf)
{
  const long idx = (long)blockIdx.x * 256 + threadIdx.x;  // half8 slots: 16*512*64
  const int lane = (int)(idx & 63);
  const long cg = idx >> 6;
  const int g = (int)(cg & 31);
  const int q = (int)((cg >> 5) & 15);
  const int gz = (int)(cg >> 9);
  const int zi = gz >> 2, zj = gz & 3;
  const int l31 = lane & 31, khi = lane >> 5;
  const int n = g * 32 + l31;
  const int k = q * 16 + khi * 8;
  const unsigned short* src = K + (long)(zi * 1024 + n) * 1024 + zj * 256 + k;
  *(half8*)(Kf + idx * 8) = *(const half8*)src;
}

// ctx = (w_pre * (1+dep[k])) @ Vb : BK=64, mfma 32x32x16, swizzled LDS (unchanged).
__global__ __launch_bounds__(256) void ctx_gemm(
    const unsigned short* __restrict__ wpre, const float* __restrict__ dep,
    const unsigned short* __restrict__ Vt, unsigned short* __restrict__ ctx)
{
  __shared__ __align__(16) unsigned short lA[2][4096];
  __shared__ __align__(16) unsigned short lB[2][4096];
  __shared__ __align__(16) unsigned short sDepH[1024];

  const int gz = blockIdx.z, zi = gz >> 2, zj = gz & 3;
  const int m0 = blockIdx.y * 128, n0 = blockIdx.x * 128;
  const int tid = threadIdx.x, wave = tid >> 6, lane = tid & 63;
  const int wm = (wave >> 1) * 64, wn = (wave & 1) * 64;
  const int srow = lane >> 2;
  const int scol = ((lane & 3) ^ ((srow >> 1) & 3)) * 8;
  const int l31 = lane & 31, khi = lane >> 5;
  const int sw2 = (l31 >> 1) & 3;

#pragma unroll
  for (int p = 0; p < 4; ++p)
    sDepH[tid + p * 256] = f2h(1.f + dep[(long)gz * 1024 + tid + p * 256]);
  __syncthreads();

  const unsigned short* Ab = wpre + (long)gz * TBB * TBB;
  const unsigned short* Bb = Vt + (long)(zj * 256) * TT + (long)zi * 1024;

  f32x16 acc[2][2] = {};

  for (int k0 = 0; k0 < 1024; k0 += 64) {
#pragma unroll
    for (int h = 0; h < 2; ++h)
#pragma unroll
      for (int t = 0; t < 2; ++t) {
        const int r = wave * 32 + t * 16 + srow;
        gl_lds16(Bb + (long)(n0 + r) * TT + (k0 + h * 32 + scol), &lB[h][wave * 1024 + t * 512]);
      }
#pragma unroll
    for (int h = 0; h < 2; ++h)
#pragma unroll
      for (int p = 0; p < 4; ++p) {
        const int idx = p * 1024 + tid * 4;
        const int row = idx >> 5, col = idx & 31;
        ushort4 wv = *(const ushort4*)(Ab + (long)(m0 + row) * 1024 + k0 + h * 32 + col);
        const half4 dv = *(const half4*)&sDepH[k0 + h * 32 + col];
        half4 pv = *(half4*)&wv * dv;
        const int pcol = (((col >> 3) ^ ((row >> 1) & 3)) << 3) | (col & 7);
        *(half4*)&lA[h][row * 32 + pcol] = pv;
      }
    __syncthreads();

    half8 af[2][4], bfr[2][4];
#pragma unroll
    for (int mi = 0; mi < 2; ++mi)
#pragma unroll
      for (int ks = 0; ks < 4; ++ks)
        af[mi][ks] = *(const half8*)&lA[ks >> 1][(wm + mi * 32 + l31) * 32 + ((((ks & 1) * 2 + khi) ^ sw2) * 8)];
#pragma unroll
    for (int ni = 0; ni < 2; ++ni)
#pragma unroll
      for (int ks = 0; ks < 4; ++ks)
        bfr[ni][ks] = *(const half8*)&lB[ks >> 1][(wn + ni * 32 + l31) * 32 + ((((ks & 1) * 2 + khi) ^ sw2) * 8)];

#pragma unroll
    for (int ks = 0; ks < 4; ++ks)
#pragma unroll
      for (int mi = 0; mi < 2; ++mi)
#pragma unroll
        for (int ni = 0; ni < 2; ++ni)
          acc[mi][ni] = __builtin_amdgcn_mfma_f32_32x32x16_f16(af[mi][ks], bfr[ni][ks], acc[mi][ni], 0, 0, 0);
    __syncthreads();
  }

  unsigned short* Cb = ctx + (long)gz * TBB * WBB;
#pragma unroll
  for (int mi = 0; mi < 2; ++mi)
#pragma unroll
    for (int ni = 0; ni < 2; ++ni)
#pragma unroll
      for (int r = 0; r < 16; ++r) {
        const int row = m0 + wm + mi * 32 + khi * 4 + (r & 3) + 8 * (r >> 2);
        const int col = n0 + wn + ni * 32 + l31;
        Cb[(long)row * WBB + col] = f2h(acc[mi][ni][r]);
      }
}

// x -> xh (fp16 row-major), xu (normalized fp16 row-major), xuf (xu in fragment order, G=128)
__global__ __launch_bounds__(256) void prepx_kernel(
    const float* __restrict__ x, unsigned short* __restrict__ xh,
    unsigned short* __restrict__ xu, unsigned short* __restrict__ xuf)
{
  const int t = blockIdx.x, tid = threadIdx.x;
  const float4 v = *((const float4*)(x + (long)t * DD) + tid);
  float ss = v.x * v.x + v.y * v.y + v.z * v.z + v.w * v.w;
  ss = waveSum(ss);
  __shared__ float red[4];
  if ((tid & 63) == 0) red[tid >> 6] = ss;
  __syncthreads();
  const float tot = red[0] + red[1] + red[2] + red[3];
  const float inv = 1.f / fmaxf(sqrtf(tot), 1e-12f);
  ushort4 h, u;
  h.x = f2h(v.x); h.y = f2h(v.y); h.z = f2h(v.z); h.w = f2h(v.w);
  u.x = f2h(v.x * inv); u.y = f2h(v.y * inv); u.z = f2h(v.z * inv); u.w = f2h(v.w * inv);
  *((ushort4*)(xh + (long)t * DD) + tid) = h;
  *((ushort4*)(xu + (long)t * DD) + tid) = u;
  const int k4 = tid * 4;
  const long c = ((long)(k4 >> 4) * 128 + (t >> 5)) * 64 + ((k4 >> 3) & 1) * 32 + (t & 31);
  *(ushort4*)(xuf + c * 8 + (k4 & 4)) = u;
}

// Wq|Wk|Wv -> fragment-order fp16 (G=32 per matrix)
__global__ __launch_bounds__(256) void castw_fw(
    const float* __restrict__ Wq, const float* __restrict__ Wk, const float* __restrict__ Wv,
    unsigned short* __restrict__ Wf)
{
  const int idx = blockIdx.x * 256 + threadIdx.x;
  const int which = idx >> 17;
  const int rem = idx & 131071;
  const int n = rem >> 7, l = rem & 127, k = l << 3;
  const float* src = ((which == 0) ? Wq : ((which == 1) ? Wk : Wv)) + (long)n * 1024 + k;
  const float4 a = ((const float4*)src)[0];
  const float4 b = ((const float4*)src)[1];
  const long c = ((long)(l >> 1) * 32 + (n >> 5)) * 64 + (l & 1) * 32 + (n & 31);
  ushort4 lo, hi;
  lo.x = f2h(a.x); lo.y = f2h(a.y); lo.z = f2h(a.z); lo.w = f2h(a.w);
  hi.x = f2h(b.x); hi.y = f2h(b.y); hi.z = f2h(b.z); hi.w = f2h(b.w);
  unsigned short* dst = Wf + ((long)which * 131072 + c) * 8;
  *(ushort4*)dst = lo;
  *(ushort4*)(dst + 4) = hi;
}

// Wout -> fragment-order fp16 (G=32)
__global__ __launch_bounds__(256) void castp_fw(const float* __restrict__ Wo,
                                               unsigned short* __restrict__ Wof)
{
  const int idx = blockIdx.x * 256 + threadIdx.x;
  const int n = idx >> 7, l = idx & 127, k = l << 3;
  const float* src = Wo + (long)n * 1024 + k;
  const float4 a = ((const float4*)src)[0];
  const float4 b = ((const float4*)src)[1];
  const long c = ((long)(l >> 1) * 32 + (n >> 5)) * 64 + (l & 1) * 32 + (n & 31);
  ushort4 lo, hi;
  lo.x = f2h(a.x); lo.y = f2h(a.y); lo.z = f2h(a.z); lo.w = f2h(a.w);
  hi.x = f2h(b.x); hi.y = f2h(b.y); hi.z = f2h(b.z); hi.w = f2h(b.w);
  unsigned short* dst = Wof + c * 8;
  *(ushort4*)dst = lo;
  *(ushort4*)(dst + 4) = hi;
}

// W2 [256 x 258] -> fragment-order fp16 (G=8) + ent/dep columns
__global__ __launch_bounds__(256) void packw2_fw(
    const float* __restrict__ W2, unsigned short* __restrict__ W2f,
    float* __restrict__ Ecol, float* __restrict__ Dcol)
{
  const int idx = blockIdx.x * 256 + threadIdx.x;
  const int n = idx >> 5, l = idx & 31, k = l << 3;
  const float* src = W2 + (long)n * 258 + k;
  const long c = ((long)(l >> 1) * 8 + (n >> 5)) * 64 + (l & 1) * 32 + (n & 31);
  unsigned short* dst = W2f + c * 8;
#pragma unroll
  for (int j = 0; j < 8; ++j) dst[j] = f2h(src[j]);
  if (l == 0) {
    Ecol[n] = W2[(long)n * 258 + 256];
    Dcol[n] = W2[(long)n * 258 + 257];
  }
}

__global__ __launch_bounds__(256) void ap_kernel(unsigned short* __restrict__ APh)
{
  const int p = blockIdx.x, tid = threadIdx.x;
#pragma unroll
  for (int t = 0; t < 4; ++t) {
    const int col = tid + t * 256;
    const int i = col >> 1;
    const float e = (2.0f * (float)i) / 1024.0f;
    const float ang = (float)p / powf(10000.0f, e);
    APh[(long)p * 1024 + col] = f2h((col & 1) ? cosf(ang) : sinf(ang));
  }
}

__global__ __launch_bounds__(256) void transpose_kernel(
    const unsigned short* __restrict__ V, unsigned short* __restrict__ Vt)
{
  __shared__ unsigned short tile[32][33];
  const int tx = threadIdx.x & 31, ty = threadIdx.x >> 5;
  const int c0 = blockIdx.x * 32;
  const int r0 = blockIdx.y * 32;
#pragma unroll
  for (int rr = ty; rr < 32; rr += 8)
    tile[rr][tx] = V[(long)(r0 + rr) * DD + c0 + tx];
  __syncthreads();
#pragma unroll
  for (int rr = ty; rr < 32; rr += 8)
    Vt[(long)(c0 + rr) * TT + r0 + tx] = tile[tx][rr];
}

// Per (gz, q-row): softmax stats (fp16 sim in) + dep + ent; writes w_pre = exp(s-m)/l fp16.
__global__ __launch_bounds__(256) void stats_kernel(
    const unsigned short* __restrict__ sim, const unsigned short* __restrict__ divb,
    float* __restrict__ dep, float* __restrict__ ent,
    unsigned short* __restrict__ wpre)
{
  const int q = blockIdx.x, gz = blockIdx.y, bi = gz >> 2;
  const int tid = threadIdx.x;
  const unsigned short* srow = sim + ((long)gz * TBB + q) * TBB;
  const unsigned short* drow = divb + ((long)bi * TBB + q) * TBB;
  const ushort4 sv = ((const ushort4*)srow)[tid];
  const ushort4 dv = ((const ushort4*)drow)[tid];
  float s[4] = {h2f(sv.x), h2f(sv.y), h2f(sv.z), h2f(sv.w)};
  float d[4] = {h2f(dv.x), h2f(dv.y), h2f(dv.z), h2f(dv.w)};
  float m = fmaxf(fmaxf(s[0], s[1]), fmaxf(s[2], s[3]));
  m = waveMax(m);
  __shared__ float red[4];
  if ((tid & 63) == 0) red[tid >> 6] = m;
  __syncthreads();
  m = fmaxf(fmaxf(red[0], red[1]), fmaxf(red[2], red[3]));
  float e[4];
  float l = 0.f, ss = 0.f, dn = 0.f, ds = 0.f;
#pragma unroll
  for (int p = 0; p < 4; ++p) {
    e[p] = expf(s[p] - m);
    l += e[p]; ss += e[p] * s[p]; dn += e[p] * d[p]; ds += d[p];
  }
  l = waveSum(l); ss = waveSum(ss); dn = waveSum(dn); ds = waveSum(ds);
  __shared__ float r2[16];
  if ((tid & 63) == 0) {
    const int w = tid >> 6;
    r2[w] = l; r2[4 + w] = ss; r2[8 + w] = dn; r2[12 + w] = ds;
  }
  __syncthreads();
  const float L = r2[0] + r2[1] + r2[2] + r2[3];
  const float Li = 1.f / L;
  ushort4 wq;
  wq.x = f2h(e[0] * Li); wq.y = f2h(e[1] * Li);
  wq.z = f2h(e[2] * Li); wq.w = f2h(e[3] * Li);
  ((ushort4*)(wpre + ((long)gz * TBB + q) * TBB))[tid] = wq;
  if (tid == 0) {
    const float SS = r2[4] + r2[5] + r2[6] + r2[7];
    const float DN = r2[8] + r2[9] + r2[10] + r2[11];
    const float DS = r2[12] + r2[13] + r2[14] + r2[15];
    const long o = (long)gz * TBB + q;
    dep[o] = (DN * Li) / DS;
    ent[o] = (m + logf(L) - SS * Li) * 0.14426950408889634f;  // 1/ln(1024)
  }
}

__global__ __launch_bounds__(256) void entnorm_kernel(float* __restrict__ ent)
{
  const int gz = blockIdx.x, tid = threadIdx.x;
  float s = 0.f;
#pragma unroll
  for (int p = 0; p < 4; ++p) s += fabsf(ent[(long)gz * TBB + tid + p * 256]);
  s = waveSum(s);
  __shared__ float red[4];
  if ((tid & 63) == 0) red[tid >> 6] = s;
  __syncthreads();
  const float scale = 1.f / fmaxf(red[0] + red[1] + red[2] + red[3], 1e-12f);
#pragma unroll
  for (int p = 0; p < 4; ++p) ent[(long)gz * TBB + tid + p * 256] *= scale;
}

extern "C" void kernel_launch(void* const* d_in, const int* in_sizes, int n_in,
                              void* d_out, int out_size, void* d_ws, size_t ws_size,
                              hipStream_t stream)
{
  const float* x  = (const float*)d_in[0];
  const float* Wq = (const float*)d_in[1];
  const float* Wk = (const float*)d_in[2];
  const float* Wv = (const float*)d_in[3];
  const float* Wo = (const float*)d_in[4];
  const float* W2 = (const float*)d_in[5];

  char* ws = (char*)d_ws;
  size_t off = 0;
  auto take = [&](size_t bytes) -> void* {
    void* p = ws + off;
    off += (bytes + 255) & ~(size_t)255;
    return p;
  };
  unsigned short* QKV = (unsigned short*)take((size_t)3 * TT * DD * 2);
  unsigned short* xh  = (unsigned short*)take((size_t)TT * DD * 2);
  unsigned short* xu  = (unsigned short*)take((size_t)TT * DD * 2);
  unsigned short* xuf = (unsigned short*)take((size_t)TT * DD * 2);
  unsigned short* Wf  = (unsigned short*)take((size_t)3 * DD * DD * 2);
  unsigned short* Wof = (unsigned short*)take((size_t)DD * DD * 2);
  unsigned short* W2f = (unsigned short*)take((size_t)256 * 256 * 2);
  float* Ecol = (float*)take(256 * 4);
  float* Dcol = (float*)take(256 * 4);
  unsigned short* APh = (unsigned short*)take((size_t)TBB * TBB * 2);
  unsigned short* divb = (unsigned short*)take((size_t)4 * TBB * TBB * 2);
  unsigned short* Vt = (unsigned short*)take((size_t)DD * TT * 2);
  unsigned short* Kf = (unsigned short*)take((size_t)TT * DD * 2);
  unsigned short* simh = (unsigned short*)take((size_t)16 * TBB * TBB * 2);
  unsigned short* wpre = (unsigned short*)take((size_t)16 * TBB * TBB * 2);
  float* depb = (float*)take((size_t)16 * TBB * 4);
  float* entb = (float*)take((size_t)16 * TBB * 4);
  unsigned short* ctx = (unsigned short*)take((size_t)16 * TBB * WBB * 2);
  unsigned short* Y = (unsigned short*)take((size_t)TT * DD * 2);
  (void)ws_size; (void)in_sizes; (void)n_in; (void)out_size;

  prepx_kernel<<<TT, 256, 0, stream>>>(x, xh, xu, xuf);
  castw_fw<<<1536, 256, 0, stream>>>(Wq, Wk, Wv, Wf);
  castp_fw<<<512, 256, 0, stream>>>(Wo, Wof);
  packw2_fw<<<32, 256, 0, stream>>>(W2, W2f, Ecol, Dcol);
  ap_kernel<<<TBB, 256, 0, stream>>>(APh);

  // QKV projection: A=xh direct, B=Wf fragment-direct, barrier-free
  gemm_dd<0, unsigned short><<<dim3(8, 32, 3), 256, 0, stream>>>(
      xh, Wf, QKV,
      DD, DD, DD, 32, 1,
      0L, 0L, 131072L, (long)TT * DD, 0L,
      nullptr, nullptr, nullptr, nullptr, nullptr);

  kf_reshape<<<2048, 256, 0, stream>>>(QKV + (size_t)TT * DD, Kf);
  transpose_kernel<<<dim3(DD / 32, TT / 32), 256, 0, stream>>>(QKV + (size_t)2 * TT * DD, Vt);

  // div diagonal blocks: 1 - xu_i @ xu_i^T, B=xuf fragment-direct
  gemm_dd<1, unsigned short><<<dim3(8, 8, 4), 256, 0, stream>>>(
      xu, xuf, divb,
      DD, DD, TBB, 128, 1,
      (long)TBB * DD, 0L, 2048L, (long)TBB * TBB, 0L,
      nullptr, nullptr, nullptr, nullptr, nullptr);

  // sim = Qb @ Kb^T + APh (fp16 out): A=Q direct, B=Kf fragment-direct
  gemm_dd<2, unsigned short><<<dim3(8, 8, 16), 256, 0, stream>>>(
      QKV, Kf, simh,
      WBB, DD, TBB, 32, 4,
      (long)TBB * DD, (long)WBB, 32768L, (long)4 * TBB * TBB, (long)TBB * TBB,
      nullptr, nullptr, nullptr, nullptr, APh);

  stats_kernel<<<dim3(TBB, 16), 256, 0, stream>>>(simh, divb, depb, entb, wpre);
  entnorm_kernel<<<16, 256, 0, stream>>>(entb);

  // ctx = (w_pre * (1+dep[k])) @ Vb
  ctx_gemm<<<dim3(2, 8, 16), 256, 0, stream>>>(wpre, depb, Vt, ctx);

  // y = [ctx | ent | dep] @ Wout2^T, B=W2f fragment-direct
  gemm_dd<3, unsigned short><<<dim3(2, 8, 16), 256, 0, stream>>>(
      ctx, W2f, Y,
      WBB, WBB, DD, 8, 4,
      (long)4 * TBB * WBB, (long)TBB * WBB, 0L, (long)TBB * DD, (long)WBB,
      entb, depb, Ecol, Dcol, nullptr);

  // out = Y @ Wout^T, B=Wof fragment-direct
  gemm_dd<0, float><<<dim3(8, 32, 1), 256, 0, stream>>>(
      Y, Wof, (float*)d_out,
      DD, DD, DD, 32, 1,
      0L, 0L, 0L, 0L, 0L,
      nullptr, nullptr, nullptr, nullptr, nullptr);
}

// Round 10
// 272.798 us; speedup vs baseline: 1.2662x; 1.2662x over previous
//
#include <hip/hip_runtime.h>
#include <hip/hip_bf16.h>

#define TT 4096
#define DD 1024
#define TBB 1024
#define WBB 256

typedef __attribute__((ext_vector_type(8))) _Float16 half8;
typedef __attribute__((ext_vector_type(4))) _Float16 half4;
typedef __attribute__((ext_vector_type(16))) float f32x16;

__device__ __forceinline__ unsigned short f2h(float v) {
  _Float16 h = (_Float16)v;
  return *reinterpret_cast<unsigned short*>(&h);
}
__device__ __forceinline__ float h2f(unsigned short u) {
  _Float16 h = *reinterpret_cast<_Float16*>(&u);
  return (float)h;
}

__device__ __forceinline__ void gl_lds16(const unsigned short* g, unsigned short* l) {
  __builtin_amdgcn_global_load_lds(
      (const __attribute__((address_space(1))) void*)(unsigned long long)(g),
      (__attribute__((address_space(3))) void*)(unsigned long long)(l),
      16, 0, 0);
}

__device__ __forceinline__ float waveSum(float v) {
#pragma unroll
  for (int o = 32; o > 0; o >>= 1) v += __shfl_down(v, o, 64);
  return v;
}
__device__ __forceinline__ float waveMax(float v) {
#pragma unroll
  for (int o = 32; o > 0; o >>= 1) v = fmaxf(v, __shfl_down(v, o, 64));
  return v;
}

// Generic C = A (MxK) * B^T (B is NxK), fp16, 128x128 tile, 4 waves,
// BK=64, mfma 32x32x16 f16, XOR bank swizzle: chunk p = c ^ ((row>>1)&3).
// (r5-verified structure: best measured GEMM core on this problem.)
// EPI: 0 plain, 1 -> 1-acc, 3 -> +ent/dep cols
template <int EPI, typename OutT>
__global__ __launch_bounds__(256) void gemm_bt(
    const unsigned short* __restrict__ A, const unsigned short* __restrict__ B,
    OutT* __restrict__ C,
    int K, int lda, int ldb, int ldc,
    int zbase, int zdiv,
    long sAi, long sAj, long sBi, long sBj, long sCi, long sCj,
    long sAz, long sBz, long sCz,
    const float* __restrict__ e0, const float* __restrict__ e1,
    const float* __restrict__ e2, const float* __restrict__ e3)
{
  __shared__ __align__(16) unsigned short lA[2][4096];
  __shared__ __align__(16) unsigned short lB[2][4096];

  const int z = blockIdx.z, gz = zbase + z;
  const int zi = gz / zdiv, zj = gz - zi * zdiv;
  const unsigned short* Ab = A + (long)zi * sAi + (long)zj * sAj + (long)z * sAz;
  const unsigned short* Bb = B + (long)zi * sBi + (long)zj * sBj + (long)z * sBz;
  const long offC = (long)zi * sCi + (long)zj * sCj + (long)z * sCz;

  const int m0 = blockIdx.y * 128, n0 = blockIdx.x * 128;
  const int tid = threadIdx.x, wave = tid >> 6, lane = tid & 63;
  const int wm = (wave >> 1) * 64, wn = (wave & 1) * 64;
  const int srow = lane >> 2;
  const int scol = (((lane & 3) ^ ((srow >> 1) & 3))) * 8;
  const int l31 = lane & 31, khi = lane >> 5;
  const int sw2 = (l31 >> 1) & 3;

  f32x16 acc[2][2] = {};

  for (int k0 = 0; k0 < K; k0 += 64) {
#pragma unroll
    for (int h = 0; h < 2; ++h)
#pragma unroll
      for (int t = 0; t < 2; ++t) {
        const int r = wave * 32 + t * 16 + srow;
        gl_lds16(Ab + (long)(m0 + r) * lda + (k0 + h * 32 + scol), &lA[h][wave * 1024 + t * 512]);
        gl_lds16(Bb + (long)(n0 + r) * ldb + (k0 + h * 32 + scol), &lB[h][wave * 1024 + t * 512]);
      }
    __syncthreads();

    half8 af[2][4], bfr[2][4];
#pragma unroll
    for (int mi = 0; mi < 2; ++mi)
#pragma unroll
      for (int ks = 0; ks < 4; ++ks)
        af[mi][ks] = *(const half8*)&lA[ks >> 1][(wm + mi * 32 + l31) * 32 + ((((ks & 1) * 2 + khi) ^ sw2) * 8)];
#pragma unroll
    for (int ni = 0; ni < 2; ++ni)
#pragma unroll
      for (int ks = 0; ks < 4; ++ks)
        bfr[ni][ks] = *(const half8*)&lB[ks >> 1][(wn + ni * 32 + l31) * 32 + ((((ks & 1) * 2 + khi) ^ sw2) * 8)];

#pragma unroll
    for (int ks = 0; ks < 4; ++ks)
#pragma unroll
      for (int mi = 0; mi < 2; ++mi)
#pragma unroll
        for (int ni = 0; ni < 2; ++ni)
          acc[mi][ni] = __builtin_amdgcn_mfma_f32_32x32x16_f16(af[mi][ks], bfr[ni][ks], acc[mi][ni], 0, 0, 0);
    __syncthreads();
  }

  OutT* Cb = C + offC;
#pragma unroll
  for (int mi = 0; mi < 2; ++mi)
#pragma unroll
    for (int ni = 0; ni < 2; ++ni)
#pragma unroll
      for (int r = 0; r < 16; ++r) {
        const int row = m0 + wm + mi * 32 + khi * 4 + (r & 3) + 8 * (r >> 2);
        const int col = n0 + wn + ni * 32 + l31;
        float v = acc[mi][ni][r];
        if constexpr (EPI == 1) v = 1.0f - v;
        if constexpr (EPI == 3)
          v += e0[(long)gz * 1024 + row] * e2[col] + e1[(long)gz * 1024 + row] * e3[col];
        const long ci = (long)row * ldc + col;
        if constexpr (sizeof(OutT) == 2) {
          Cb[ci] = (OutT)f2h(v);
        } else {
          Cb[ci] = v;
        }
      }
}

// sim GEMM: C(fp16) = A*B^T + APh (fp16 abs-pos), both operands LDS-staged, swizzled.
__global__ __launch_bounds__(256) void sim_gemm(
    const unsigned short* __restrict__ A, const unsigned short* __restrict__ B,
    unsigned short* __restrict__ C,
    const unsigned short* __restrict__ APh)
{
  __shared__ __align__(16) unsigned short lA[2][4096];
  __shared__ __align__(16) unsigned short lB[2][4096];

  const int gz = blockIdx.z;
  const int zi = gz >> 2, zj = gz & 3;
  const unsigned short* Ab = A + (long)zi * (TBB * DD) + zj * WBB;
  const unsigned short* Bb = B + (long)zi * (TBB * DD) + zj * WBB;
  unsigned short* Cb = C + (long)gz * TBB * TBB;

  const int m0 = blockIdx.y * 128, n0 = blockIdx.x * 128;
  const int tid = threadIdx.x, wave = tid >> 6, lane = tid & 63;
  const int wm = (wave >> 1) * 64, wn = (wave & 1) * 64;
  const int srow = lane >> 2;
  const int scol = ((lane & 3) ^ ((srow >> 1) & 3)) * 8;
  const int l31 = lane & 31, khi = lane >> 5;
  const int sw2 = (l31 >> 1) & 3;

  f32x16 acc[2][2] = {};

  for (int k0 = 0; k0 < WBB; k0 += 64) {
#pragma unroll
    for (int h = 0; h < 2; ++h)
#pragma unroll
      for (int t = 0; t < 2; ++t) {
        const int r = wave * 32 + t * 16 + srow;
        gl_lds16(Ab + (long)(m0 + r) * DD + (k0 + h * 32 + scol), &lA[h][wave * 1024 + t * 512]);
        gl_lds16(Bb + (long)(n0 + r) * DD + (k0 + h * 32 + scol), &lB[h][wave * 1024 + t * 512]);
      }
    __syncthreads();

    half8 af[2][4], bfr[2][4];
#pragma unroll
    for (int mi = 0; mi < 2; ++mi)
#pragma unroll
      for (int ks = 0; ks < 4; ++ks)
        af[mi][ks] = *(const half8*)&lA[ks >> 1][(wm + mi * 32 + l31) * 32 + ((((ks & 1) * 2 + khi) ^ sw2) * 8)];
#pragma unroll
    for (int ni = 0; ni < 2; ++ni)
#pragma unroll
      for (int ks = 0; ks < 4; ++ks)
        bfr[ni][ks] = *(const half8*)&lB[ks >> 1][(wn + ni * 32 + l31) * 32 + ((((ks & 1) * 2 + khi) ^ sw2) * 8)];

#pragma unroll
    for (int ks = 0; ks < 4; ++ks)
#pragma unroll
      for (int mi = 0; mi < 2; ++mi)
#pragma unroll
        for (int ni = 0; ni < 2; ++ni)
          acc[mi][ni] = __builtin_amdgcn_mfma_f32_32x32x16_f16(af[mi][ks], bfr[ni][ks], acc[mi][ni], 0, 0, 0);
    __syncthreads();
  }

#pragma unroll
  for (int mi = 0; mi < 2; ++mi)
#pragma unroll
    for (int ni = 0; ni < 2; ++ni)
#pragma unroll
      for (int r = 0; r < 16; ++r) {
        const int row = m0 + wm + mi * 32 + khi * 4 + (r & 3) + 8 * (r >> 2);
        const int col = n0 + wn + ni * 32 + l31;
        Cb[(long)row * TBB + col] = f2h(acc[mi][ni][r] + h2f(APh[(long)row * 1024 + col]));
      }
}

// ctx = (w_pre * (1+dep[k])) @ Vb : BK=64, mfma 32x32x16, swizzled LDS.
__global__ __launch_bounds__(256) void ctx_gemm(
    const unsigned short* __restrict__ wpre, const float* __restrict__ dep,
    const unsigned short* __restrict__ Vt, unsigned short* __restrict__ ctx)
{
  __shared__ __align__(16) unsigned short lA[2][4096];
  __shared__ __align__(16) unsigned short lB[2][4096];
  __shared__ __align__(16) unsigned short sDepH[1024];

  const int gz = blockIdx.z, zi = gz >> 2, zj = gz & 3;
  const int m0 = blockIdx.y * 128, n0 = blockIdx.x * 128;
  const int tid = threadIdx.x, wave = tid >> 6, lane = tid & 63;
  const int wm = (wave >> 1) * 64, wn = (wave & 1) * 64;
  const int srow = lane >> 2;
  const int scol = ((lane & 3) ^ ((srow >> 1) & 3)) * 8;
  const int l31 = lane & 31, khi = lane >> 5;
  const int sw2 = (l31 >> 1) & 3;

#pragma unroll
  for (int p = 0; p < 4; ++p)
    sDepH[tid + p * 256] = f2h(1.f + dep[(long)gz * 1024 + tid + p * 256]);
  __syncthreads();

  const unsigned short* Ab = wpre + (long)gz * TBB * TBB;
  const unsigned short* Bb = Vt + (long)(zj * 256) * TT + (long)zi * 1024;

  f32x16 acc[2][2] = {};

  for (int k0 = 0; k0 < 1024; k0 += 64) {
#pragma unroll
    for (int h = 0; h < 2; ++h)
#pragma unroll
      for (int t = 0; t < 2; ++t) {
        const int r = wave * 32 + t * 16 + srow;
        gl_lds16(Bb + (long)(n0 + r) * TT + (k0 + h * 32 + scol), &lB[h][wave * 1024 + t * 512]);
      }
#pragma unroll
    for (int h = 0; h < 2; ++h)
#pragma unroll
      for (int p = 0; p < 4; ++p) {
        const int idx = p * 1024 + tid * 4;
        const int row = idx >> 5, col = idx & 31;
        ushort4 wv = *(const ushort4*)(Ab + (long)(m0 + row) * 1024 + k0 + h * 32 + col);
        const half4 dv = *(const half4*)&sDepH[k0 + h * 32 + col];
        half4 pv = *(half4*)&wv * dv;
        const int pcol = (((col >> 3) ^ ((row >> 1) & 3)) << 3) | (col & 7);
        *(half4*)&lA[h][row * 32 + pcol] = pv;
      }
    __syncthreads();

    half8 af[2][4], bfr[2][4];
#pragma unroll
    for (int mi = 0; mi < 2; ++mi)
#pragma unroll
      for (int ks = 0; ks < 4; ++ks)
        af[mi][ks] = *(const half8*)&lA[ks >> 1][(wm + mi * 32 + l31) * 32 + ((((ks & 1) * 2 + khi) ^ sw2) * 8)];
#pragma unroll
    for (int ni = 0; ni < 2; ++ni)
#pragma unroll
      for (int ks = 0; ks < 4; ++ks)
        bfr[ni][ks] = *(const half8*)&lB[ks >> 1][(wn + ni * 32 + l31) * 32 + ((((ks & 1) * 2 + khi) ^ sw2) * 8)];

#pragma unroll
    for (int ks = 0; ks < 4; ++ks)
#pragma unroll
      for (int mi = 0; mi < 2; ++mi)
#pragma unroll
        for (int ni = 0; ni < 2; ++ni)
          acc[mi][ni] = __builtin_amdgcn_mfma_f32_32x32x16_f16(af[mi][ks], bfr[ni][ks], acc[mi][ni], 0, 0, 0);
    __syncthreads();
  }

  unsigned short* Cb = ctx + (long)gz * TBB * WBB;
#pragma unroll
  for (int mi = 0; mi < 2; ++mi)
#pragma unroll
    for (int ni = 0; ni < 2; ++ni)
#pragma unroll
      for (int r = 0; r < 16; ++r) {
        const int row = m0 + wm + mi * 32 + khi * 4 + (r & 3) + 8 * (r >> 2);
        const int col = n0 + wn + ni * 32 + l31;
        Cb[(long)row * WBB + col] = f2h(acc[mi][ni][r]);
      }
}

__global__ __launch_bounds__(256) void prepx_kernel(
    const float* __restrict__ x, unsigned short* __restrict__ xh,
    unsigned short* __restrict__ xu)
{
  const int t = blockIdx.x, tid = threadIdx.x;
  const float4 v = *((const float4*)(x + (long)t * DD) + tid);
  float ss = v.x * v.x + v.y * v.y + v.z * v.z + v.w * v.w;
  ss = waveSum(ss);
  __shared__ float red[4];
  if ((tid & 63) == 0) red[tid >> 6] = ss;
  __syncthreads();
  const float tot = red[0] + red[1] + red[2] + red[3];
  const float inv = 1.f / fmaxf(sqrtf(tot), 1e-12f);
  ushort4 h, u;
  h.x = f2h(v.x); h.y = f2h(v.y); h.z = f2h(v.z); h.w = f2h(v.w);
  u.x = f2h(v.x * inv); u.y = f2h(v.y * inv); u.z = f2h(v.z * inv); u.w = f2h(v.w * inv);
  *((ushort4*)(xh + (long)t * DD) + tid) = h;
  *((ushort4*)(xu + (long)t * DD) + tid) = u;
}

__global__ __launch_bounds__(256) void castw_kernel(
    const float* __restrict__ Wq, const float* __restrict__ Wk, const float* __restrict__ Wv,
    unsigned short* __restrict__ o)
{
  const long idx4 = ((long)blockIdx.x * 256 + threadIdx.x) * 4;
  const int which = (int)(idx4 >> 20);
  const long loc = idx4 & ((1L << 20) - 1);
  const float* src = (which == 0) ? Wq : ((which == 1) ? Wk : Wv);
  const float4 v = *(const float4*)(src + loc);
  ushort4 h;
  h.x = f2h(v.x); h.y = f2h(v.y); h.z = f2h(v.z); h.w = f2h(v.w);
  *(ushort4*)(o + idx4) = h;
}

__global__ __launch_bounds__(256) void castp_kernel(const float* __restrict__ src,
                                                    unsigned short* __restrict__ dst)
{
  const long idx4 = ((long)blockIdx.x * 256 + threadIdx.x) * 4;
  const float4 v = *(const float4*)(src + idx4);
  ushort4 h;
  h.x = f2h(v.x); h.y = f2h(v.y); h.z = f2h(v.z); h.w = f2h(v.w);
  *(ushort4*)(dst + idx4) = h;
}

__global__ __launch_bounds__(256) void packw2_kernel(
    const float* __restrict__ W2, unsigned short* __restrict__ W2B,
    float* __restrict__ Ecol, float* __restrict__ Dcol)
{
  const int c = blockIdx.x, j = threadIdx.x;
  W2B[c * 256 + j] = f2h(W2[c * 258 + j]);
  if (j == 0) {
    Ecol[c] = W2[c * 258 + 256];
    Dcol[c] = W2[c * 258 + 257];
  }
}

__global__ __launch_bounds__(256) void ap_kernel(unsigned short* __restrict__ APh)
{
  const int p = blockIdx.x, tid = threadIdx.x;
#pragma unroll
  for (int t = 0; t < 4; ++t) {
    const int col = tid + t * 256;
    const int i = col >> 1;
    const float e = (2.0f * (float)i) / 1024.0f;
    const float ang = (float)p / powf(10000.0f, e);
    APh[(long)p * 1024 + col] = f2h((col & 1) ? cosf(ang) : sinf(ang));
  }
}

__global__ __launch_bounds__(256) void transpose_kernel(
    const unsigned short* __restrict__ V, unsigned short* __restrict__ Vt)
{
  __shared__ unsigned short tile[32][33];
  const int tx = threadIdx.x & 31, ty = threadIdx.x >> 5;
  const int c0 = blockIdx.x * 32;
  const int r0 = blockIdx.y * 32;
#pragma unroll
  for (int rr = ty; rr < 32; rr += 8)
    tile[rr][tx] = V[(long)(r0 + rr) * DD + c0 + tx];
  __syncthreads();
#pragma unroll
  for (int rr = ty; rr < 32; rr += 8)
    Vt[(long)(c0 + rr) * TT + r0 + tx] = tile[tx][rr];
}

// Per (gz, q-row): softmax stats (fp16 sim in) + dep + ent; writes w_pre = exp(s-m)/l fp16.
__global__ __launch_bounds__(256) void stats_kernel(
    const unsigned short* __restrict__ sim, const unsigned short* __restrict__ divb,
    float* __restrict__ dep, float* __restrict__ ent,
    unsigned short* __restrict__ wpre)
{
  const int q = blockIdx.x, gz = blockIdx.y, bi = gz >> 2;
  const int tid = threadIdx.x;
  const unsigned short* srow = sim + ((long)gz * TBB + q) * TBB;
  const unsigned short* drow = divb + ((long)bi * TBB + q) * TBB;
  const ushort4 sv = ((const ushort4*)srow)[tid];
  const ushort4 dv = ((const ushort4*)drow)[tid];
  float s[4] = {h2f(sv.x), h2f(sv.y), h2f(sv.z), h2f(sv.w)};
  float d[4] = {h2f(dv.x), h2f(dv.y), h2f(dv.z), h2f(dv.w)};
  float m = fmaxf(fmaxf(s[0], s[1]), fmaxf(s[2], s[3]));
  m = waveMax(m);
  __shared__ float red[4];
  if ((tid & 63) == 0) red[tid >> 6] = m;
  __syncthreads();
  m = fmaxf(fmaxf(red[0], red[1]), fmaxf(red[2], red[3]));
  float e[4];
  float l = 0.f, ss = 0.f, dn = 0.f, ds = 0.f;
#pragma unroll
  for (int p = 0; p < 4; ++p) {
    e[p] = expf(s[p] - m);
    l += e[p]; ss += e[p] * s[p]; dn += e[p] * d[p]; ds += d[p];
  }
  l = waveSum(l); ss = waveSum(ss); dn = waveSum(dn); ds = waveSum(ds);
  __shared__ float r2[16];
  if ((tid & 63) == 0) {
    const int w = tid >> 6;
    r2[w] = l; r2[4 + w] = ss; r2[8 + w] = dn; r2[12 + w] = ds;
  }
  __syncthreads();
  const float L = r2[0] + r2[1] + r2[2] + r2[3];
  const float Li = 1.f / L;
  ushort4 wq;
  wq.x = f2h(e[0] * Li); wq.y = f2h(e[1] * Li);
  wq.z = f2h(e[2] * Li); wq.w = f2h(e[3] * Li);
  ((ushort4*)(wpre + ((long)gz * TBB + q) * TBB))[tid] = wq;
  if (tid == 0) {
    const float SS = r2[4] + r2[5] + r2[6] + r2[7];
    const float DN = r2[8] + r2[9] + r2[10] + r2[11];
    const float DS = r2[12] + r2[13] + r2[14] + r2[15];
    const long o = (long)gz * TBB + q;
    dep[o] = (DN * Li) / DS;
    ent[o] = (m + logf(L) - SS * Li) * 0.14426950408889634f;  // 1/ln(1024)
  }
}

__global__ __launch_bounds__(256) void entnorm_kernel(float* __restrict__ ent)
{
  const int gz = blockIdx.x, tid = threadIdx.x;
  float s = 0.f;
#pragma unroll
  for (int p = 0; p < 4; ++p) s += fabsf(ent[(long)gz * TBB + tid + p * 256]);
  s = waveSum(s);
  __shared__ float red[4];
  if ((tid & 63) == 0) red[tid >> 6] = s;
  __syncthreads();
  const float scale = 1.f / fmaxf(red[0] + red[1] + red[2] + red[3], 1e-12f);
#pragma unroll
  for (int p = 0; p < 4; ++p) ent[(long)gz * TBB + tid + p * 256] *= scale;
}

extern "C" void kernel_launch(void* const* d_in, const int* in_sizes, int n_in,
                              void* d_out, int out_size, void* d_ws, size_t ws_size,
                              hipStream_t stream)
{
  const float* x  = (const float*)d_in[0];
  const float* Wq = (const float*)d_in[1];
  const float* Wk = (const float*)d_in[2];
  const float* Wv = (const float*)d_in[3];
  const float* Wo = (const float*)d_in[4];
  const float* W2 = (const float*)d_in[5];

  char* ws = (char*)d_ws;
  size_t off = 0;
  auto take = [&](size_t bytes) -> void* {
    void* p = ws + off;
    off += (bytes + 255) & ~(size_t)255;
    return p;
  };
  unsigned short* QKV = (unsigned short*)take((size_t)3 * TT * DD * 2);
  unsigned short* xh  = (unsigned short*)take((size_t)TT * DD * 2);
  unsigned short* xu  = (unsigned short*)take((size_t)TT * DD * 2);
  unsigned short* Wh  = (unsigned short*)take((size_t)3 * DD * DD * 2);
  unsigned short* WoB = (unsigned short*)take((size_t)DD * DD * 2);
  unsigned short* W2B = (unsigned short*)take((size_t)256 * 256 * 2);
  float* Ecol = (float*)take(256 * 4);
  float* Dcol = (float*)take(256 * 4);
  unsigned short* APh = (unsigned short*)take((size_t)TBB * TBB * 2);
  unsigned short* divb = (unsigned short*)take((size_t)4 * TBB * TBB * 2);
  unsigned short* Vt = (unsigned short*)take((size_t)DD * TT * 2);
  unsigned short* simh = (unsigned short*)take((size_t)16 * TBB * TBB * 2);
  unsigned short* wpre = (unsigned short*)take((size_t)16 * TBB * TBB * 2);
  float* depb = (float*)take((size_t)16 * TBB * 4);
  float* entb = (float*)take((size_t)16 * TBB * 4);
  unsigned short* ctx = (unsigned short*)take((size_t)16 * TBB * WBB * 2);
  unsigned short* Y = (unsigned short*)take((size_t)TT * DD * 2);
  (void)ws_size; (void)in_sizes; (void)n_in; (void)out_size;

  prepx_kernel<<<TT, 256, 0, stream>>>(x, xh, xu);
  castw_kernel<<<(3 * DD * DD) / 1024, 256, 0, stream>>>(Wq, Wk, Wv, Wh);
  castp_kernel<<<(DD * DD) / 1024, 256, 0, stream>>>(Wo, WoB);
  packw2_kernel<<<256, 256, 0, stream>>>(W2, W2B, Ecol, Dcol);
  ap_kernel<<<TBB, 256, 0, stream>>>(APh);

  // QKV projection: Q|K|V [4096,1024] each, fp16
  gemm_bt<0, unsigned short><<<dim3(DD / 128, TT / 128, 3), 256, 0, stream>>>(
      xh, Wh, QKV,
      DD, DD, DD, DD, 0, 1,
      0, 0, (long)DD * DD, 0, (long)TT * DD, 0,
      0, 0, 0, nullptr, nullptr, nullptr, nullptr);

  transpose_kernel<<<dim3(DD / 32, TT / 32), 256, 0, stream>>>(QKV + (size_t)2 * TT * DD, Vt);

  // div diagonal blocks: 1 - xu_i @ xu_i^T, fp16 out
  gemm_bt<1, unsigned short><<<dim3(8, 8, 4), 256, 0, stream>>>(
      xu, xu, divb,
      DD, DD, DD, TBB, 0, 1,
      (long)TBB * DD, 0, (long)TBB * DD, 0, (long)TBB * TBB, 0,
      0, 0, 0, nullptr, nullptr, nullptr, nullptr);

  const unsigned short* Qh = QKV;
  const unsigned short* Kh = QKV + (size_t)TT * DD;

  // sim = Qb @ Kb^T + APh (fp16 out), all 16 blocks
  sim_gemm<<<dim3(8, 8, 16), 256, 0, stream>>>(Qh, Kh, simh, APh);

  stats_kernel<<<dim3(TBB, 16), 256, 0, stream>>>(simh, divb, depb, entb, wpre);
  entnorm_kernel<<<16, 256, 0, stream>>>(entb);

  // ctx = (w_pre * (1+dep[k])) @ Vb
  ctx_gemm<<<dim3(2, 8, 16), 256, 0, stream>>>(wpre, depb, Vt, ctx);

  // y = [ctx | ent | dep] @ Wout2^T, scattered back to [4096,1024]
  gemm_bt<3, unsigned short><<<dim3(2, 8, 16), 256, 0, stream>>>(
      ctx, W2B, Y,
      WBB, WBB, WBB, DD, 0, 4,
      (long)4 * TBB * WBB, (long)TBB * WBB, 0, 0, (long)TBB * DD, (long)WBB,
      0, 0, 0, entb, depb, Ecol, Dcol);

  // out = Y @ Wout^T
  gemm_bt<0, float><<<dim3(8, 32, 1), 256, 0, stream>>>(
      Y, WoB, (float*)d_out,
      DD, DD, DD, DD, 0, 1,
      0, 0, 0, 0, 0, 0,
      0, 0, 0, nullptr, nullptr, nullptr, nullptr);
}

// Round 11
// 266.313 us; speedup vs baseline: 1.2971x; 1.0244x over previous
//
#include <hip/hip_runtime.h>
#include <hip/hip_bf16.h>

#define TT 4096
#define DD 1024
#define TBB 1024
#define WBB 256

typedef __attribute__((ext_vector_type(8))) _Float16 half8;
typedef __attribute__((ext_vector_type(4))) _Float16 half4;
typedef __attribute__((ext_vector_type(16))) float f32x16;

__device__ __forceinline__ unsigned short f2h(float v) {
  _Float16 h = (_Float16)v;
  return *reinterpret_cast<unsigned short*>(&h);
}
__device__ __forceinline__ float h2f(unsigned short u) {
  _Float16 h = *reinterpret_cast<_Float16*>(&u);
  return (float)h;
}

__device__ __forceinline__ void gl_lds16(const unsigned short* g, unsigned short* l) {
  __builtin_amdgcn_global_load_lds(
      (const __attribute__((address_space(1))) void*)(unsigned long long)(g),
      (__attribute__((address_space(3))) void*)(unsigned long long)(l),
      16, 0, 0);
}

__device__ __forceinline__ float waveSum(float v) {
#pragma unroll
  for (int o = 32; o > 0; o >>= 1) v += __shfl_down(v, o, 64);
  return v;
}
__device__ __forceinline__ float waveMax(float v) {
#pragma unroll
  for (int o = 32; o > 0; o >>= 1) v = fmaxf(v, __shfl_down(v, o, 64));
  return v;
}

// Generic C = A (MxK) * B^T, fp16, 128x128 tile, 4 waves, BK=64,
// mfma 32x32x16 f16, XOR bank swizzle. (r5-verified best core; used for QKV.)
// EPI: 0 plain
template <int EPI, typename OutT>
__global__ __launch_bounds__(256) void gemm_bt(
    const unsigned short* __restrict__ A, const unsigned short* __restrict__ B,
    OutT* __restrict__ C,
    int K, int lda, int ldb, int ldc,
    int zbase, int zdiv,
    long sAi, long sAj, long sBi, long sBj, long sCi, long sCj,
    long sAz, long sBz, long sCz,
    const float* __restrict__ e0, const float* __restrict__ e1,
    const float* __restrict__ e2, const float* __restrict__ e3)
{
  __shared__ __align__(16) unsigned short lA[2][4096];
  __shared__ __align__(16) unsigned short lB[2][4096];

  const int z = blockIdx.z, gz = zbase + z;
  const int zi = gz / zdiv, zj = gz - zi * zdiv;
  const unsigned short* Ab = A + (long)zi * sAi + (long)zj * sAj + (long)z * sAz;
  const unsigned short* Bb = B + (long)zi * sBi + (long)zj * sBj + (long)z * sBz;
  const long offC = (long)zi * sCi + (long)zj * sCj + (long)z * sCz;

  const int m0 = blockIdx.y * 128, n0 = blockIdx.x * 128;
  const int tid = threadIdx.x, wave = tid >> 6, lane = tid & 63;
  const int wm = (wave >> 1) * 64, wn = (wave & 1) * 64;
  const int srow = lane >> 2;
  const int scol = (((lane & 3) ^ ((srow >> 1) & 3))) * 8;
  const int l31 = lane & 31, khi = lane >> 5;
  const int sw2 = (l31 >> 1) & 3;

  f32x16 acc[2][2] = {};

  for (int k0 = 0; k0 < K; k0 += 64) {
#pragma unroll
    for (int h = 0; h < 2; ++h)
#pragma unroll
      for (int t = 0; t < 2; ++t) {
        const int r = wave * 32 + t * 16 + srow;
        gl_lds16(Ab + (long)(m0 + r) * lda + (k0 + h * 32 + scol), &lA[h][wave * 1024 + t * 512]);
        gl_lds16(Bb + (long)(n0 + r) * ldb + (k0 + h * 32 + scol), &lB[h][wave * 1024 + t * 512]);
      }
    __syncthreads();

    half8 af[2][4], bfr[2][4];
#pragma unroll
    for (int mi = 0; mi < 2; ++mi)
#pragma unroll
      for (int ks = 0; ks < 4; ++ks)
        af[mi][ks] = *(const half8*)&lA[ks >> 1][(wm + mi * 32 + l31) * 32 + ((((ks & 1) * 2 + khi) ^ sw2) * 8)];
#pragma unroll
    for (int ni = 0; ni < 2; ++ni)
#pragma unroll
      for (int ks = 0; ks < 4; ++ks)
        bfr[ni][ks] = *(const half8*)&lB[ks >> 1][(wn + ni * 32 + l31) * 32 + ((((ks & 1) * 2 + khi) ^ sw2) * 8)];

#pragma unroll
    for (int ks = 0; ks < 4; ++ks)
#pragma unroll
      for (int mi = 0; mi < 2; ++mi)
#pragma unroll
        for (int ni = 0; ni < 2; ++ni)
          acc[mi][ni] = __builtin_amdgcn_mfma_f32_32x32x16_f16(af[mi][ks], bfr[ni][ks], acc[mi][ni], 0, 0, 0);
    __syncthreads();
  }

  OutT* Cb = C + offC;
#pragma unroll
  for (int mi = 0; mi < 2; ++mi)
#pragma unroll
    for (int ni = 0; ni < 2; ++ni)
#pragma unroll
      for (int r = 0; r < 16; ++r) {
        const int row = m0 + wm + mi * 32 + khi * 4 + (r & 3) + 8 * (r >> 2);
        const int col = n0 + wn + ni * 32 + l31;
        float v = acc[mi][ni][r];
        const long ci = (long)row * ldc + col;
        if constexpr (sizeof(OutT) == 2) {
          Cb[ci] = (OutT)f2h(v);
        } else {
          Cb[ci] = v;
        }
      }
}

// Small-tile GEMM for occupancy: 64x64 tile, 4 waves (each one 32x32 quadrant),
// BK=64, swizzled LDS (16 KB), grid 4x larger than 128-tile -> 4 blocks/CU.
// For the latency-bound kernels that had 1 block/CU (div, ctx-y, out).
// EPI: 0 plain, 1 -> 1-acc, 3 -> +ent/dep cols
template <int EPI, typename OutT>
__global__ __launch_bounds__(256) void gemm_s(
    const unsigned short* __restrict__ A, const unsigned short* __restrict__ B,
    OutT* __restrict__ C,
    int K, int lda, int ldb, int ldc,
    int zbase, int zdiv,
    long sAi, long sAj, long sBi, long sBj, long sCi, long sCj,
    long sAz, long sBz, long sCz,
    const float* __restrict__ e0, const float* __restrict__ e1,
    const float* __restrict__ e2, const float* __restrict__ e3)
{
  __shared__ __align__(16) unsigned short lA[2][2048];
  __shared__ __align__(16) unsigned short lB[2][2048];

  const int z = blockIdx.z, gz = zbase + z;
  const int zi = gz / zdiv, zj = gz - zi * zdiv;
  const unsigned short* Ab = A + (long)zi * sAi + (long)zj * sAj + (long)z * sAz;
  const unsigned short* Bb = B + (long)zi * sBi + (long)zj * sBj + (long)z * sBz;
  const long offC = (long)zi * sCi + (long)zj * sCj + (long)z * sCz;

  const int m0 = blockIdx.y * 64, n0 = blockIdx.x * 64;
  const int tid = threadIdx.x, wave = tid >> 6, lane = tid & 63;
  const int wm = (wave >> 1) * 32, wn = (wave & 1) * 32;
  const int srow = lane >> 2;                       // staging row within wave's 16-row slice
  const int grow = wave * 16 + srow;                // global staging row 0..63
  const int scol = (((lane & 3) ^ ((grow >> 1) & 3))) * 8;
  const int l31 = lane & 31, khi = lane >> 5;
  const int sw2 = (l31 >> 1) & 3;

  f32x16 acc = {};

  for (int k0 = 0; k0 < K; k0 += 64) {
#pragma unroll
    for (int h = 0; h < 2; ++h) {
      gl_lds16(Ab + (long)(m0 + grow) * lda + (k0 + h * 32 + scol), &lA[h][wave * 512]);
      gl_lds16(Bb + (long)(n0 + grow) * ldb + (k0 + h * 32 + scol), &lB[h][wave * 512]);
    }
    __syncthreads();

    half8 af[4], bfr[4];
#pragma unroll
    for (int ks = 0; ks < 4; ++ks) {
      af[ks] = *(const half8*)&lA[ks >> 1][(wm + l31) * 32 + ((((ks & 1) * 2 + khi) ^ sw2) * 8)];
      bfr[ks] = *(const half8*)&lB[ks >> 1][(wn + l31) * 32 + ((((ks & 1) * 2 + khi) ^ sw2) * 8)];
    }
#pragma unroll
    for (int ks = 0; ks < 4; ++ks)
      acc = __builtin_amdgcn_mfma_f32_32x32x16_f16(af[ks], bfr[ks], acc, 0, 0, 0);
    __syncthreads();
  }

  OutT* Cb = C + offC;
#pragma unroll
  for (int r = 0; r < 16; ++r) {
    const int row = m0 + wm + khi * 4 + (r & 3) + 8 * (r >> 2);
    const int col = n0 + wn + l31;
    float v = acc[r];
    if constexpr (EPI == 1) v = 1.0f - v;
    if constexpr (EPI == 3)
      v += e0[(long)gz * 1024 + row] * e2[col] + e1[(long)gz * 1024 + row] * e3[col];
    const long ci = (long)row * ldc + col;
    if constexpr (sizeof(OutT) == 2) {
      Cb[ci] = (OutT)f2h(v);
    } else {
      Cb[ci] = v;
    }
  }
}

// sim GEMM: C(fp16) = A*B^T + APh, 128x128, LDS-staged, swizzled. (4/CU already.)
__global__ __launch_bounds__(256) void sim_gemm(
    const unsigned short* __restrict__ A, const unsigned short* __restrict__ B,
    unsigned short* __restrict__ C,
    const unsigned short* __restrict__ APh)
{
  __shared__ __align__(16) unsigned short lA[2][4096];
  __shared__ __align__(16) unsigned short lB[2][4096];

  const int gz = blockIdx.z;
  const int zi = gz >> 2, zj = gz & 3;
  const unsigned short* Ab = A + (long)zi * (TBB * DD) + zj * WBB;
  const unsigned short* Bb = B + (long)zi * (TBB * DD) + zj * WBB;
  unsigned short* Cb = C + (long)gz * TBB * TBB;

  const int m0 = blockIdx.y * 128, n0 = blockIdx.x * 128;
  const int tid = threadIdx.x, wave = tid >> 6, lane = tid & 63;
  const int wm = (wave >> 1) * 64, wn = (wave & 1) * 64;
  const int srow = lane >> 2;
  const int scol = ((lane & 3) ^ ((srow >> 1) & 3)) * 8;
  const int l31 = lane & 31, khi = lane >> 5;
  const int sw2 = (l31 >> 1) & 3;

  f32x16 acc[2][2] = {};

  for (int k0 = 0; k0 < WBB; k0 += 64) {
#pragma unroll
    for (int h = 0; h < 2; ++h)
#pragma unroll
      for (int t = 0; t < 2; ++t) {
        const int r = wave * 32 + t * 16 + srow;
        gl_lds16(Ab + (long)(m0 + r) * DD + (k0 + h * 32 + scol), &lA[h][wave * 1024 + t * 512]);
        gl_lds16(Bb + (long)(n0 + r) * DD + (k0 + h * 32 + scol), &lB[h][wave * 1024 + t * 512]);
      }
    __syncthreads();

    half8 af[2][4], bfr[2][4];
#pragma unroll
    for (int mi = 0; mi < 2; ++mi)
#pragma unroll
      for (int ks = 0; ks < 4; ++ks)
        af[mi][ks] = *(const half8*)&lA[ks >> 1][(wm + mi * 32 + l31) * 32 + ((((ks & 1) * 2 + khi) ^ sw2) * 8)];
#pragma unroll
    for (int ni = 0; ni < 2; ++ni)
#pragma unroll
      for (int ks = 0; ks < 4; ++ks)
        bfr[ni][ks] = *(const half8*)&lB[ks >> 1][(wn + ni * 32 + l31) * 32 + ((((ks & 1) * 2 + khi) ^ sw2) * 8)];

#pragma unroll
    for (int ks = 0; ks < 4; ++ks)
#pragma unroll
      for (int mi = 0; mi < 2; ++mi)
#pragma unroll
        for (int ni = 0; ni < 2; ++ni)
          acc[mi][ni] = __builtin_amdgcn_mfma_f32_32x32x16_f16(af[mi][ks], bfr[ni][ks], acc[mi][ni], 0, 0, 0);
    __syncthreads();
  }

#pragma unroll
  for (int mi = 0; mi < 2; ++mi)
#pragma unroll
    for (int ni = 0; ni < 2; ++ni)
#pragma unroll
      for (int r = 0; r < 16; ++r) {
        const int row = m0 + wm + mi * 32 + khi * 4 + (r & 3) + 8 * (r >> 2);
        const int col = n0 + wn + ni * 32 + l31;
        Cb[(long)row * TBB + col] = f2h(acc[mi][ni][r] + h2f(APh[(long)row * 1024 + col]));
      }
}

// ctx = (w_pre * (1+dep[k])) @ Vb : 64x64 tile version (4 blocks/CU), swizzled LDS.
__global__ __launch_bounds__(256) void ctx_gemm_s(
    const unsigned short* __restrict__ wpre, const float* __restrict__ dep,
    const unsigned short* __restrict__ Vt, unsigned short* __restrict__ ctx)
{
  __shared__ __align__(16) unsigned short lA[2][2048];
  __shared__ __align__(16) unsigned short lB[2][2048];
  __shared__ __align__(16) unsigned short sDepH[1024];

  const int gz = blockIdx.z, zi = gz >> 2, zj = gz & 3;
  const int m0 = blockIdx.y * 64, n0 = blockIdx.x * 64;
  const int tid = threadIdx.x, wave = tid >> 6, lane = tid & 63;
  const int wm = (wave >> 1) * 32, wn = (wave & 1) * 32;
  const int srow = lane >> 2;
  const int grow = wave * 16 + srow;
  const int scol = ((lane & 3) ^ ((grow >> 1) & 3)) * 8;
  const int l31 = lane & 31, khi = lane >> 5;
  const int sw2 = (l31 >> 1) & 3;

#pragma unroll
  for (int p = 0; p < 4; ++p)
    sDepH[tid + p * 256] = f2h(1.f + dep[(long)gz * 1024 + tid + p * 256]);
  __syncthreads();

  const unsigned short* Ab = wpre + (long)gz * TBB * TBB;
  const unsigned short* Bb = Vt + (long)(zj * 256) * TT + (long)zi * 1024;

  f32x16 acc = {};

  for (int k0 = 0; k0 < 1024; k0 += 64) {
#pragma unroll
    for (int h = 0; h < 2; ++h)
      gl_lds16(Bb + (long)(n0 + grow) * TT + (k0 + h * 32 + scol), &lB[h][wave * 512]);
#pragma unroll
    for (int h = 0; h < 2; ++h)
#pragma unroll
      for (int p = 0; p < 2; ++p) {
        const int idx = p * 1024 + tid * 4;
        const int row = idx >> 5, col = idx & 31;
        ushort4 wv = *(const ushort4*)(Ab + (long)(m0 + row) * 1024 + k0 + h * 32 + col);
        const half4 dv = *(const half4*)&sDepH[k0 + h * 32 + col];
        half4 pv = *(half4*)&wv * dv;
        const int pcol = (((col >> 3) ^ ((row >> 1) & 3)) << 3) | (col & 7);
        *(half4*)&lA[h][row * 32 + pcol] = pv;
      }
    __syncthreads();

    half8 af[4], bfr[4];
#pragma unroll
    for (int ks = 0; ks < 4; ++ks) {
      af[ks] = *(const half8*)&lA[ks >> 1][(wm + l31) * 32 + ((((ks & 1) * 2 + khi) ^ sw2) * 8)];
      bfr[ks] = *(const half8*)&lB[ks >> 1][(wn + l31) * 32 + ((((ks & 1) * 2 + khi) ^ sw2) * 8)];
    }
#pragma unroll
    for (int ks = 0; ks < 4; ++ks)
      acc = __builtin_amdgcn_mfma_f32_32x32x16_f16(af[ks], bfr[ks], acc, 0, 0, 0);
    __syncthreads();
  }

  unsigned short* Cb = ctx + (long)gz * TBB * WBB;
#pragma unroll
  for (int r = 0; r < 16; ++r) {
    const int row = m0 + wm + khi * 4 + (r & 3) + 8 * (r >> 2);
    const int col = n0 + wn + l31;
    Cb[(long)row * WBB + col] = f2h(acc[r]);
  }
}

__global__ __launch_bounds__(256) void prepx_kernel(
    const float* __restrict__ x, unsigned short* __restrict__ xh,
    unsigned short* __restrict__ xu)
{
  const int t = blockIdx.x, tid = threadIdx.x;
  const float4 v = *((const float4*)(x + (long)t * DD) + tid);
  float ss = v.x * v.x + v.y * v.y + v.z * v.z + v.w * v.w;
  ss = waveSum(ss);
  __shared__ float red[4];
  if ((tid & 63) == 0) red[tid >> 6] = ss;
  __syncthreads();
  const float tot = red[0] + red[1] + red[2] + red[3];
  const float inv = 1.f / fmaxf(sqrtf(tot), 1e-12f);
  ushort4 h, u;
  h.x = f2h(v.x); h.y = f2h(v.y); h.z = f2h(v.z); h.w = f2h(v.w);
  u.x = f2h(v.x * inv); u.y = f2h(v.y * inv); u.z = f2h(v.z * inv); u.w = f2h(v.w * inv);
  *((ushort4*)(xh + (long)t * DD) + tid) = h;
  *((ushort4*)(xu + (long)t * DD) + tid) = u;
}

__global__ __launch_bounds__(256) void castw_kernel(
    const float* __restrict__ Wq, const float* __restrict__ Wk, const float* __restrict__ Wv,
    unsigned short* __restrict__ o)
{
  const long idx4 = ((long)blockIdx.x * 256 + threadIdx.x) * 4;
  const int which = (int)(idx4 >> 20);
  const long loc = idx4 & ((1L << 20) - 1);
  const float* src = (which == 0) ? Wq : ((which == 1) ? Wk : Wv);
  const float4 v = *(const float4*)(src + loc);
  ushort4 h;
  h.x = f2h(v.x); h.y = f2h(v.y); h.z = f2h(v.z); h.w = f2h(v.w);
  *(ushort4*)(o + idx4) = h;
}

__global__ __launch_bounds__(256) void castp_kernel(const float* __restrict__ src,
                                                    unsigned short* __restrict__ dst)
{
  const long idx4 = ((long)blockIdx.x * 256 + threadIdx.x) * 4;
  const float4 v = *(const float4*)(src + idx4);
  ushort4 h;
  h.x = f2h(v.x); h.y = f2h(v.y); h.z = f2h(v.z); h.w = f2h(v.w);
  *(ushort4*)(dst + idx4) = h;
}

__global__ __launch_bounds__(256) void packw2_kernel(
    const float* __restrict__ W2, unsigned short* __restrict__ W2B,
    float* __restrict__ Ecol, float* __restrict__ Dcol)
{
  const int c = blockIdx.x, j = threadIdx.x;
  W2B[c * 256 + j] = f2h(W2[c * 258 + j]);
  if (j == 0) {
    Ecol[c] = W2[c * 258 + 256];
    Dcol[c] = W2[c * 258 + 257];
  }
}

__global__ __launch_bounds__(256) void ap_kernel(unsigned short* __restrict__ APh)
{
  const int p = blockIdx.x, tid = threadIdx.x;
#pragma unroll
  for (int t = 0; t < 4; ++t) {
    const int col = tid + t * 256;
    const int i = col >> 1;
    const float e = (2.0f * (float)i) / 1024.0f;
    const float ang = (float)p / powf(10000.0f, e);
    APh[(long)p * 1024 + col] = f2h((col & 1) ? cosf(ang) : sinf(ang));
  }
}

__global__ __launch_bounds__(256) void transpose_kernel(
    const unsigned short* __restrict__ V, unsigned short* __restrict__ Vt)
{
  __shared__ unsigned short tile[32][33];
  const int tx = threadIdx.x & 31, ty = threadIdx.x >> 5;
  const int c0 = blockIdx.x * 32;
  const int r0 = blockIdx.y * 32;
#pragma unroll
  for (int rr = ty; rr < 32; rr += 8)
    tile[rr][tx] = V[(long)(r0 + rr) * DD + c0 + tx];
  __syncthreads();
#pragma unroll
  for (int rr = ty; rr < 32; rr += 8)
    Vt[(long)(c0 + rr) * TT + r0 + tx] = tile[tx][rr];
}

// Per (gz, q-row): softmax stats (fp16 sim in) + dep + ent; writes w_pre = exp(s-m)/l fp16.
__global__ __launch_bounds__(256) void stats_kernel(
    const unsigned short* __restrict__ sim, const unsigned short* __restrict__ divb,
    float* __restrict__ dep, float* __restrict__ ent,
    unsigned short* __restrict__ wpre)
{
  const int q = blockIdx.x, gz = blockIdx.y, bi = gz >> 2;
  const int tid = threadIdx.x;
  const unsigned short* srow = sim + ((long)gz * TBB + q) * TBB;
  const unsigned short* drow = divb + ((long)bi * TBB + q) * TBB;
  const ushort4 sv = ((const ushort4*)srow)[tid];
  const ushort4 dv = ((const ushort4*)drow)[tid];
  float s[4] = {h2f(sv.x), h2f(sv.y), h2f(sv.z), h2f(sv.w)};
  float d[4] = {h2f(dv.x), h2f(dv.y), h2f(dv.z), h2f(dv.w)};
  float m = fmaxf(fmaxf(s[0], s[1]), fmaxf(s[2], s[3]));
  m = waveMax(m);
  __shared__ float red[4];
  if ((tid & 63) == 0) red[tid >> 6] = m;
  __syncthreads();
  m = fmaxf(fmaxf(red[0], red[1]), fmaxf(red[2], red[3]));
  float e[4];
  float l = 0.f, ss = 0.f, dn = 0.f, ds = 0.f;
#pragma unroll
  for (int p = 0; p < 4; ++p) {
    e[p] = expf(s[p] - m);
    l += e[p]; ss += e[p] * s[p]; dn += e[p] * d[p]; ds += d[p];
  }
  l = waveSum(l); ss = waveSum(ss); dn = waveSum(dn); ds = waveSum(ds);
  __shared__ float r2[16];
  if ((tid & 63) == 0) {
    const int w = tid >> 6;
    r2[w] = l; r2[4 + w] = ss; r2[8 + w] = dn; r2[12 + w] = ds;
  }
  __syncthreads();
  const float L = r2[0] + r2[1] + r2[2] + r2[3];
  const float Li = 1.f / L;
  ushort4 wq;
  wq.x = f2h(e[0] * Li); wq.y = f2h(e[1] * Li);
  wq.z = f2h(e[2] * Li); wq.w = f2h(e[3] * Li);
  ((ushort4*)(wpre + ((long)gz * TBB + q) * TBB))[tid] = wq;
  if (tid == 0) {
    const float SS = r2[4] + r2[5] + r2[6] + r2[7];
    const float DN = r2[8] + r2[9] + r2[10] + r2[11];
    const float DS = r2[12] + r2[13] + r2[14] + r2[15];
    const long o = (long)gz * TBB + q;
    dep[o] = (DN * Li) / DS;
    ent[o] = (m + logf(L) - SS * Li) * 0.14426950408889634f;  // 1/ln(1024)
  }
}

__global__ __launch_bounds__(256) void entnorm_kernel(float* __restrict__ ent)
{
  const int gz = blockIdx.x, tid = threadIdx.x;
  float s = 0.f;
#pragma unroll
  for (int p = 0; p < 4; ++p) s += fabsf(ent[(long)gz * TBB + tid + p * 256]);
  s = waveSum(s);
  __shared__ float red[4];
  if ((tid & 63) == 0) red[tid >> 6] = s;
  __syncthreads();
  const float scale = 1.f / fmaxf(red[0] + red[1] + red[2] + red[3], 1e-12f);
#pragma unroll
  for (int p = 0; p < 4; ++p) ent[(long)gz * TBB + tid + p * 256] *= scale;
}

extern "C" void kernel_launch(void* const* d_in, const int* in_sizes, int n_in,
                              void* d_out, int out_size, void* d_ws, size_t ws_size,
                              hipStream_t stream)
{
  const float* x  = (const float*)d_in[0];
  const float* Wq = (const float*)d_in[1];
  const float* Wk = (const float*)d_in[2];
  const float* Wv = (const float*)d_in[3];
  const float* Wo = (const float*)d_in[4];
  const float* W2 = (const float*)d_in[5];

  char* ws = (char*)d_ws;
  size_t off = 0;
  auto take = [&](size_t bytes) -> void* {
    void* p = ws + off;
    off += (bytes + 255) & ~(size_t)255;
    return p;
  };
  unsigned short* QKV = (unsigned short*)take((size_t)3 * TT * DD * 2);
  unsigned short* xh  = (unsigned short*)take((size_t)TT * DD * 2);
  unsigned short* xu  = (unsigned short*)take((size_t)TT * DD * 2);
  unsigned short* Wh  = (unsigned short*)take((size_t)3 * DD * DD * 2);
  unsigned short* WoB = (unsigned short*)take((size_t)DD * DD * 2);
  unsigned short* W2B = (unsigned short*)take((size_t)256 * 256 * 2);
  float* Ecol = (float*)take(256 * 4);
  float* Dcol = (float*)take(256 * 4);
  unsigned short* APh = (unsigned short*)take((size_t)TBB * TBB * 2);
  unsigned short* divb = (unsigned short*)take((size_t)4 * TBB * TBB * 2);
  unsigned short* Vt = (unsigned short*)take((size_t)DD * TT * 2);
  unsigned short* simh = (unsigned short*)take((size_t)16 * TBB * TBB * 2);
  unsigned short* wpre = (unsigned short*)take((size_t)16 * TBB * TBB * 2);
  float* depb = (float*)take((size_t)16 * TBB * 4);
  float* entb = (float*)take((size_t)16 * TBB * 4);
  unsigned short* ctx = (unsigned short*)take((size_t)16 * TBB * WBB * 2);
  unsigned short* Y = (unsigned short*)take((size_t)TT * DD * 2);
  (void)ws_size; (void)in_sizes; (void)n_in; (void)out_size;

  prepx_kernel<<<TT, 256, 0, stream>>>(x, xh, xu);
  castw_kernel<<<(3 * DD * DD) / 1024, 256, 0, stream>>>(Wq, Wk, Wv, Wh);
  castp_kernel<<<(DD * DD) / 1024, 256, 0, stream>>>(Wo, WoB);
  packw2_kernel<<<256, 256, 0, stream>>>(W2, W2B, Ecol, Dcol);
  ap_kernel<<<TBB, 256, 0, stream>>>(APh);

  // QKV projection: 128-tile core (3 blocks/CU, best measured)
  gemm_bt<0, unsigned short><<<dim3(DD / 128, TT / 128, 3), 256, 0, stream>>>(
      xh, Wh, QKV,
      DD, DD, DD, DD, 0, 1,
      0, 0, (long)DD * DD, 0, (long)TT * DD, 0,
      0, 0, 0, nullptr, nullptr, nullptr, nullptr);

  transpose_kernel<<<dim3(DD / 32, TT / 32), 256, 0, stream>>>(QKV + (size_t)2 * TT * DD, Vt);

  // div diagonal blocks: 1 - xu_i @ xu_i^T, fp16 out — 64-tile, 4 blocks/CU
  gemm_s<1, unsigned short><<<dim3(16, 16, 4), 256, 0, stream>>>(
      xu, xu, divb,
      DD, DD, DD, TBB, 0, 1,
      (long)TBB * DD, 0, (long)TBB * DD, 0, (long)TBB * TBB, 0,
      0, 0, 0, nullptr, nullptr, nullptr, nullptr);

  const unsigned short* Qh = QKV;
  const unsigned short* Kh = QKV + (size_t)TT * DD;

  // sim = Qb @ Kb^T + APh (fp16 out), all 16 blocks (4 blocks/CU already)
  sim_gemm<<<dim3(8, 8, 16), 256, 0, stream>>>(Qh, Kh, simh, APh);

  stats_kernel<<<dim3(TBB, 16), 256, 0, stream>>>(simh, divb, depb, entb, wpre);
  entnorm_kernel<<<16, 256, 0, stream>>>(entb);

  // ctx = (w_pre * (1+dep[k])) @ Vb — 64-tile, 4 blocks/CU
  ctx_gemm_s<<<dim3(4, 16, 16), 256, 0, stream>>>(wpre, depb, Vt, ctx);

  // y = [ctx | ent | dep] @ Wout2^T — 64-tile, 4 blocks/CU
  gemm_s<3, unsigned short><<<dim3(4, 16, 16), 256, 0, stream>>>(
      ctx, W2B, Y,
      WBB, WBB, WBB, DD, 0, 4,
      (long)4 * TBB * WBB, (long)TBB * WBB, 0, 0, (long)TBB * DD, (long)WBB,
      0, 0, 0, entb, depb, Ecol, Dcol);

  // out = Y @ Wout^T — 64-tile, 4 blocks/CU
  gemm_s<0, float><<<dim3(16, 64, 1), 256, 0, stream>>>(
      Y, WoB, (float*)d_out,
      DD, DD, DD, DD, 0, 1,
      0, 0, 0, 0, 0, 0,
      0, 0, 0, nullptr, nullptr, nullptr, nullptr);
}